// Round 8
// baseline (163.397 us; speedup 1.0000x reference)
//
#include <hip/hip_runtime.h>
#include <hip/hip_bf16.h>

#define N_NODES 50000
#define N_EDGES 800000
#define IN_DIM  256
#define OUT_DIM 128

#define NBINS        1024     // R16: bins of 49 rows: 1024*49 = 50176 >= 50000
#define ROWS_PER_BIN 49
#define BIN_CAP      1056     // mean 781 + ~10 sigma
#define EPB          2048     // edges per bin-block
#define NB_BIN       391      // ceil(800000/2048)
#define NB_GEMM      782      // 1 wave = 1 tile, 4 tiles/block (R12, verified)
#define CUR_STRIDE   32       // one 128B cacheline per bin cursor

typedef __bf16 bf16x8 __attribute__((ext_vector_type(8)));
typedef float  f32x4  __attribute__((ext_vector_type(4)));

// R16 bin = floor(row/49) via magic: (r*85599)>>22, exact for r < 50176:
// ceil-magic theorem: m=ceil(2^22/49)=85599, (m*49-2^22)=47, 47*50176<2^22 ok;
// max product 50175*85599=4294929825 < 2^32.  (Same constant family as the
// verified /196 (>>24, R5-R7) and /98 (>>23, R14) magics.)
__device__ __forceinline__ unsigned bin_of(unsigned r) { return (r * 85599u) >> 22; }
__device__ __forceinline__ float blo(unsigned u) { return __uint_as_float(u << 16); }
__device__ __forceinline__ float bhi(unsigned u) { return __uint_as_float(u & 0xffff0000u); }

// ---------------------------------------------------------------------------
// ws layout (bytes)
// ---------------------------------------------------------------------------
#define WF_OFF   0                      // 64 KB    : Wf bf16 frag-order [4096 slots][8]
#define SUP_OFF  65536                  // 12.8 MB  : support u32 [50000][64] planar-pair
#define BIN_OFF  12865536               // 8.65 MB  : binbuf int2[1024*1056]
#define CUR_OFF  21516288               // 128 KB   : bin_cursor int[1024*CUR_STRIDE]

// ---------------------------------------------------------------------------
// prep (R12, verified): Wf = W in MFMA B-fragment order.
// Slot s (16B = 8 halfs): n = s>>9, ks = (s>>6)&7, lane = s&63, m = lane&15,
// quad = (lane>>4); half j holds W[(quad*8+ks*32+j)*OUT_DIM + (n*16+m)].
// ---------------------------------------------------------------------------
__global__ void k_prep(const float* __restrict__ W, __bf16* __restrict__ Wf,
                       int* __restrict__ bin_cursor) {
    int t = blockIdx.x * 256 + threadIdx.x;
    if (t < 32768) {
        int s = t >> 3, j = t & 7;
        int nrow = ((s >> 9) << 4) | (s & 15);                 // n*16 + m
        int k    = (((s >> 4) & 3) << 3) | (((s >> 6) & 7) << 5) | j;
        Wf[t] = (__bf16)W[k * OUT_DIM + nrow];
    }
    if (t < NBINS) bin_cursor[t * CUR_STRIDE] = t * BIN_CAP;
}

// ---------------------------------------------------------------------------
// k_fuse (R15, verified structure): gemm and bin co-run in one dispatch.
//   blocks [0, NB_GEMM):        R12 gemm body, verbatim.
//   blocks [NB_GEMM, +NB_BIN):  lean bin body (1024-bin plumbing).
// ---------------------------------------------------------------------------
__global__ __launch_bounds__(256, 2) void k_fuse(const float* __restrict__ x,
                                                 const __bf16* __restrict__ Wf,
                                                 unsigned* __restrict__ sup32,
                                                 const int* __restrict__ rows,
                                                 const int* __restrict__ cols,
                                                 const float* __restrict__ vals,
                                                 int* __restrict__ bin_cursor,
                                                 int2* __restrict__ binbuf) {
    __shared__ union {
        uint4 sB[4096];                                   // 64 KB : gemm Wf tile
        struct { int cur[NBINS]; int base[NBINS]; } bin;  // 8 KB  : bin counters
    } sh;
    int t = threadIdx.x;

    if (blockIdx.x < NB_GEMM) {
        // ---------------- gemm path (R12, verified) ----------------
        const uint4* wf4 = (const uint4*)Wf;
#pragma unroll
        for (int r = 0; r < 16; ++r) sh.sB[r * 256 + t] = wf4[r * 256 + t];
        __syncthreads();

        int  wave = t >> 6;
        int  lane = t & 63;
        long tile = (long)blockIdx.x * 4 + wave;       // 0..3127
        if (tile >= 3125) return;                      // after the barrier: safe
        int  m    = lane & 15;
        int  quad = lane >> 4;

        // A: lane (m,quad) reads row tile*16+m; 3125*16 == 50000 -> no guard.
        const float* aprow = x + (tile * 16 + m) * IN_DIM + quad * 8;

        float4 fa[16];
#pragma unroll
        for (int ks = 0; ks < 8; ++ks) {
            fa[2 * ks]     = *(const float4*)(aprow + ks * 32);
            fa[2 * ks + 1] = *(const float4*)(aprow + ks * 32 + 4);
        }
        bf16x8 ab[8];
#pragma unroll
        for (int ks = 0; ks < 8; ++ks) {
            float4 f0 = fa[2 * ks];
            float4 f1 = fa[2 * ks + 1];
            ab[ks] = (bf16x8){(__bf16)f0.x, (__bf16)f0.y, (__bf16)f0.z, (__bf16)f0.w,
                              (__bf16)f1.x, (__bf16)f1.y, (__bf16)f1.z, (__bf16)f1.w};
        }

        f32x4 acc[8];
#pragma unroll
        for (int n = 0; n < 8; ++n) acc[n] = (f32x4){0, 0, 0, 0};

        const __bf16* sbh = (const __bf16*)sh.sB;
#pragma unroll
        for (int ks = 0; ks < 8; ++ks) {
#pragma unroll
            for (int n = 0; n < 8; ++n) {
                // slot (n*8+ks)*64 + lane : consecutive lanes -> consecutive 16B
                bf16x8 bfr = *(const bf16x8*)(sbh + (((n * 8 + ks) * 64 + lane) << 3));
                acc[n] = __builtin_amdgcn_mfma_f32_16x16x32_bf16(ab[ks], bfr, acc[n], 0, 0, 0);
            }
        }

        // planar-pair epilogue (verified R7): word j = n*16+m = ch j | ch j+64
        unsigned* op = sup32 + (long)tile * 16 * 64;
#pragma unroll
        for (int r = 0; r < 4; ++r) {
#pragma unroll
            for (int n = 0; n < 4; ++n) {
                __bf16 lo = (__bf16)acc[n][r], hi = (__bf16)acc[n + 4][r];
                unsigned w = (unsigned)*(unsigned short*)&lo |
                             ((unsigned)*(unsigned short*)&hi << 16);
                op[(quad * 4 + r) * 64 + n * 16 + m] = w;
            }
        }
    } else {
        // ---------------- bin path (lean, 1024 bins) ----------------
        long e0 = (long)(blockIdx.x - NB_GEMM) * EPB;
        sh.bin.cur[t]       = 0; sh.bin.cur[t + 256] = 0;
        sh.bin.cur[t + 512] = 0; sh.bin.cur[t + 768] = 0;
        __syncthreads();

        int2 rec[8];
        int  lrank[8];
        bool full = (e0 + EPB <= N_EDGES);   // true for 390 of 391 blocks

        if (full) {
#pragma unroll
            for (int k = 0; k < 8; ++k) {
                long e = e0 + k * 256 + t;
                unsigned r = (unsigned)rows[e];
                unsigned c = (unsigned)cols[e];
                float    w = vals[e];
                rec[k]   = make_int2((int)((r << 16) | c), __float_as_int(w));
                lrank[k] = atomicAdd(&sh.bin.cur[bin_of(r)], 1);
            }
        } else {
#pragma unroll
            for (int k = 0; k < 8; ++k) {
                long e = e0 + k * 256 + t;
                lrank[k] = -1;
                if (e < N_EDGES) {
                    unsigned r = (unsigned)rows[e];
                    unsigned c = (unsigned)cols[e];
                    float    w = vals[e];
                    rec[k]   = make_int2((int)((r << 16) | c), __float_as_int(w));
                    lrank[k] = atomicAdd(&sh.bin.cur[bin_of(r)], 1);
                }
            }
        }
        __syncthreads();

#pragma unroll
        for (int q = 0; q < 4; ++q) {
            int bi = t + q * 256;
            sh.bin.base[bi] = atomicAdd(&bin_cursor[bi * CUR_STRIDE], sh.bin.cur[bi]);
        }
        __syncthreads();

        if (full) {
#pragma unroll
            for (int k = 0; k < 8; ++k) {
                unsigned bn = bin_of(((unsigned)rec[k].x) >> 16);
                int dst = sh.bin.base[bn] + lrank[k];
                if (dst < (int)(bn + 1) * BIN_CAP)
                    binbuf[dst] = rec[k];
            }
        } else {
#pragma unroll
            for (int k = 0; k < 8; ++k) {
                if (lrank[k] >= 0) {
                    unsigned bn = bin_of(((unsigned)rec[k].x) >> 16);
                    int dst = sh.bin.base[bn] + lrank[k];
                    if (dst < (int)(bn + 1) * BIN_CAP)
                        binbuf[dst] = rec[k];
                }
            }
        }
    }
}

// ---------------------------------------------------------------------------
// k_sg (R16): 1024 bins of 49 rows -> 1024 blocks = 4 blocks/CU (R15 was
// grid-limited at 2/CU, Occupancy 28.6%).  Gather inner loop = verified R14.
// LDS ~17 KB/block.
// ---------------------------------------------------------------------------
__global__ __launch_bounds__(512, 4) void k_sg(const int* __restrict__ bin_cursor,
                                               const int2* __restrict__ binbuf,
                                               const unsigned* __restrict__ sup,
                                               const float* __restrict__ bias,
                                               float* __restrict__ out) {
    __shared__ int2 stage[BIN_CAP];                // 8.4 KB
    __shared__ int2 sorted_[BIN_CAP];              // 8.4 KB
    __shared__ int  cnt[64], off[64], cur[64], s[64];
    int b = blockIdx.x, t = threadIdx.x;
    int row0 = b * ROWS_PER_BIN;

    int n = bin_cursor[b * CUR_STRIDE] - b * BIN_CAP;
    n = n < 0 ? 0 : (n > BIN_CAP ? BIN_CAP : n);
    const int2* seg = binbuf + (long)b * BIN_CAP;

    if (t < 64) cnt[t] = 0;
    __syncthreads();

    for (int i = t; i < n; i += 512) {
        int2 rec = seg[i];
        stage[i] = rec;
        atomicAdd(&cnt[(int)(((unsigned)rec.x) >> 16) - row0], 1);
    }
    __syncthreads();

    int v = 0;
    if (t < 64) { v = cnt[t]; s[t] = v; }
    __syncthreads();
#pragma unroll
    for (int o = 1; o < 64; o <<= 1) {
        int xv = 0;
        if (t < 64 && t >= o) xv = s[t - o];
        __syncthreads();
        if (t < 64) s[t] += xv;
        __syncthreads();
    }
    if (t < 64) { off[t] = s[t] - v; cur[t] = 0; }
    __syncthreads();

    for (int i = t; i < n; i += 512) {
        int2 rec = stage[i];
        int rl = (int)(((unsigned)rec.x) >> 16) - row0;
        sorted_[off[rl] + atomicAdd(&cur[rl], 1)] = rec;
    }
    __syncthreads();

    int wave = t >> 6, lane = t & 63;
    float bb0 = bias[lane], bb1 = bias[64 + lane];

    for (int rl = wave; rl < ROWS_PER_BIN; rl += 8) {
        int row = row0 + rl;
        if (row >= N_NODES) continue;
        int st = off[rl], nd = cnt[rl];
        float a0 = 0.f, a1 = 0.f;
        for (int i = 0; i < nd; i += 16) {
            int cidx[16]; unsigned u[16]; float vv[16];
#pragma unroll
            for (int j = 0; j < 16; ++j) {
                int ok = (i + j) < nd;
                int2 rec = sorted_[ok ? st + i + j : st];
                cidx[j] = rec.x & 0xffff;
                vv[j]   = ok ? __int_as_float(rec.y) : 0.f;
            }
#pragma unroll
            for (int j = 0; j < 16; ++j)
                u[j] = sup[(long)cidx[j] * 64 + lane];
#pragma unroll
            for (int j = 0; j < 16; ++j) {
                a0 += vv[j] * blo(u[j]);
                a1 += vv[j] * bhi(u[j]);
            }
        }
        out[(long)row * 128 + lane]      = a0 + bb0;
        out[(long)row * 128 + 64 + lane] = a1 + bb1;
    }
}

// ---------------------------------------------------------------------------
extern "C" void kernel_launch(void* const* d_in, const int* in_sizes, int n_in,
                              void* d_out, int out_size, void* d_ws, size_t ws_size,
                              hipStream_t stream) {
    const int*   adj_rows = (const int*)  d_in[0];
    const int*   adj_cols = (const int*)  d_in[1];
    const float* adj_vals = (const float*)d_in[2];
    const float* x        = (const float*)d_in[3];
    const float* W        = (const float*)d_in[4];
    const float* b        = (const float*)d_in[5];
    float* out = (float*)d_out;

    char* ws = (char*)d_ws;
    __bf16*   Wf         = (__bf16*)  (ws + WF_OFF);
    unsigned* sup32      = (unsigned*)(ws + SUP_OFF);
    int2*     binbuf     = (int2*)    (ws + BIN_OFF);
    int*      bin_cursor = (int*)     (ws + CUR_OFF);

    k_prep<<<128, 256, 0, stream>>>(W, Wf, bin_cursor);
    k_fuse<<<NB_GEMM + NB_BIN, 256, 0, stream>>>(x, Wf, sup32,
                                                 adj_rows, adj_cols, adj_vals,
                                                 bin_cursor, binbuf);
    k_sg  <<<NBINS, 512, 0, stream>>>(bin_cursor, binbuf, sup32, b, out);
}

// Round 9
// 151.617 us; speedup vs baseline: 1.0777x; 1.0777x over previous
//
#include <hip/hip_runtime.h>
#include <hip/hip_bf16.h>

#define N_NODES 50000
#define N_EDGES 800000
#define IN_DIM  256
#define OUT_DIM 128

#define NBINS        512      // bins of 98 rows: 512*98 = 50176 >= 50000 (R15, verified)
#define ROWS_PER_BIN 98
#define HALF_ROWS    49       // R17: k_sg processes half a bin per block
#define BIN_CAP      1920     // mean 1563 + 9 sigma
#define EPB          2048     // edges per bin-block
#define NB_BIN       391      // ceil(800000/2048)
#define NB_GEMM      782      // 1 wave = 1 tile, 4 tiles/block (R12, verified)
#define CUR_STRIDE   32       // one 128B cacheline per bin cursor

typedef __bf16 bf16x8 __attribute__((ext_vector_type(8)));
typedef float  f32x4  __attribute__((ext_vector_type(4)));

// bin = floor(row/98) via magic: (r*85599)>>23, exact for r < 50176 (verified R14).
__device__ __forceinline__ unsigned bin_of(unsigned r) { return (r * 85599u) >> 23; }
__device__ __forceinline__ float blo(unsigned u) { return __uint_as_float(u << 16); }
__device__ __forceinline__ float bhi(unsigned u) { return __uint_as_float(u & 0xffff0000u); }

// ---------------------------------------------------------------------------
// ws layout (bytes)
// ---------------------------------------------------------------------------
#define WF_OFF   0                      // 64 KB    : Wf bf16 frag-order [4096 slots][8]
#define SUP_OFF  65536                  // 12.8 MB  : support u32 [50000][64] planar-pair
#define BIN_OFF  12865536               // 7.86 MB  : binbuf int2[512*1920]
#define CUR_OFF  20729856               // 64 KB    : bin_cursor int[512*CUR_STRIDE]

// ---------------------------------------------------------------------------
// prep (R12, verified): Wf = W in MFMA B-fragment order.
// Slot s (16B = 8 halfs): n = s>>9, ks = (s>>6)&7, lane = s&63, m = lane&15,
// quad = (lane>>4); half j holds W[(quad*8+ks*32+j)*OUT_DIM + (n*16+m)].
// ---------------------------------------------------------------------------
__global__ void k_prep(const float* __restrict__ W, __bf16* __restrict__ Wf,
                       int* __restrict__ bin_cursor) {
    int t = blockIdx.x * 256 + threadIdx.x;
    if (t < 32768) {
        int s = t >> 3, j = t & 7;
        int nrow = ((s >> 9) << 4) | (s & 15);                 // n*16 + m
        int k    = (((s >> 4) & 3) << 3) | (((s >> 6) & 7) << 5) | j;
        Wf[t] = (__bf16)W[k * OUT_DIM + nrow];
    }
    if (t < NBINS) bin_cursor[t * CUR_STRIDE] = t * BIN_CAP;
}

// ---------------------------------------------------------------------------
// k_fuse (R15, verified — best measured config): gemm and bin co-run.
//   blocks [0, NB_GEMM):        R12 gemm body, verbatim.
//   blocks [NB_GEMM, +NB_BIN):  R14 512-bin lean bin body, verbatim.
// ---------------------------------------------------------------------------
__global__ __launch_bounds__(256, 2) void k_fuse(const float* __restrict__ x,
                                                 const __bf16* __restrict__ Wf,
                                                 unsigned* __restrict__ sup32,
                                                 const int* __restrict__ rows,
                                                 const int* __restrict__ cols,
                                                 const float* __restrict__ vals,
                                                 int* __restrict__ bin_cursor,
                                                 int2* __restrict__ binbuf) {
    __shared__ union {
        uint4 sB[4096];                                   // 64 KB : gemm Wf tile
        struct { int cur[NBINS]; int base[NBINS]; } bin;  // 4 KB  : bin counters
    } sh;
    int t = threadIdx.x;

    if (blockIdx.x < NB_GEMM) {
        // ---------------- gemm path (R12, verified) ----------------
        const uint4* wf4 = (const uint4*)Wf;
#pragma unroll
        for (int r = 0; r < 16; ++r) sh.sB[r * 256 + t] = wf4[r * 256 + t];
        __syncthreads();

        int  wave = t >> 6;
        int  lane = t & 63;
        long tile = (long)blockIdx.x * 4 + wave;       // 0..3127
        if (tile >= 3125) return;                      // after the barrier: safe
        int  m    = lane & 15;
        int  quad = lane >> 4;

        // A: lane (m,quad) reads row tile*16+m; 3125*16 == 50000 -> no guard.
        const float* aprow = x + (tile * 16 + m) * IN_DIM + quad * 8;

        float4 fa[16];
#pragma unroll
        for (int ks = 0; ks < 8; ++ks) {
            fa[2 * ks]     = *(const float4*)(aprow + ks * 32);
            fa[2 * ks + 1] = *(const float4*)(aprow + ks * 32 + 4);
        }
        bf16x8 ab[8];
#pragma unroll
        for (int ks = 0; ks < 8; ++ks) {
            float4 f0 = fa[2 * ks];
            float4 f1 = fa[2 * ks + 1];
            ab[ks] = (bf16x8){(__bf16)f0.x, (__bf16)f0.y, (__bf16)f0.z, (__bf16)f0.w,
                              (__bf16)f1.x, (__bf16)f1.y, (__bf16)f1.z, (__bf16)f1.w};
        }

        f32x4 acc[8];
#pragma unroll
        for (int n = 0; n < 8; ++n) acc[n] = (f32x4){0, 0, 0, 0};

        const __bf16* sbh = (const __bf16*)sh.sB;
#pragma unroll
        for (int ks = 0; ks < 8; ++ks) {
#pragma unroll
            for (int n = 0; n < 8; ++n) {
                // slot (n*8+ks)*64 + lane : consecutive lanes -> consecutive 16B
                bf16x8 bfr = *(const bf16x8*)(sbh + (((n * 8 + ks) * 64 + lane) << 3));
                acc[n] = __builtin_amdgcn_mfma_f32_16x16x32_bf16(ab[ks], bfr, acc[n], 0, 0, 0);
            }
        }

        // planar-pair epilogue (verified R7): word j = n*16+m = ch j | ch j+64
        unsigned* op = sup32 + (long)tile * 16 * 64;
#pragma unroll
        for (int r = 0; r < 4; ++r) {
#pragma unroll
            for (int n = 0; n < 4; ++n) {
                __bf16 lo = (__bf16)acc[n][r], hi = (__bf16)acc[n + 4][r];
                unsigned w = (unsigned)*(unsigned short*)&lo |
                             ((unsigned)*(unsigned short*)&hi << 16);
                op[(quad * 4 + r) * 64 + n * 16 + m] = w;
            }
        }
    } else {
        // ---------------- bin path (R14 512-bin, verified) ----------------
        long e0 = (long)(blockIdx.x - NB_GEMM) * EPB;
        sh.bin.cur[t] = 0; sh.bin.cur[t + 256] = 0;
        __syncthreads();

        int2 rec[8];
        int  lrank[8];
        bool full = (e0 + EPB <= N_EDGES);   // true for 390 of 391 blocks

        if (full) {
#pragma unroll
            for (int k = 0; k < 8; ++k) {
                long e = e0 + k * 256 + t;
                unsigned r = (unsigned)rows[e];
                unsigned c = (unsigned)cols[e];
                float    w = vals[e];
                rec[k]   = make_int2((int)((r << 16) | c), __float_as_int(w));
                lrank[k] = atomicAdd(&sh.bin.cur[bin_of(r)], 1);
            }
        } else {
#pragma unroll
            for (int k = 0; k < 8; ++k) {
                long e = e0 + k * 256 + t;
                lrank[k] = -1;
                if (e < N_EDGES) {
                    unsigned r = (unsigned)rows[e];
                    unsigned c = (unsigned)cols[e];
                    float    w = vals[e];
                    rec[k]   = make_int2((int)((r << 16) | c), __float_as_int(w));
                    lrank[k] = atomicAdd(&sh.bin.cur[bin_of(r)], 1);
                }
            }
        }
        __syncthreads();

        sh.bin.base[t]       = atomicAdd(&bin_cursor[t * CUR_STRIDE],         sh.bin.cur[t]);
        sh.bin.base[t + 256] = atomicAdd(&bin_cursor[(t + 256) * CUR_STRIDE], sh.bin.cur[t + 256]);
        __syncthreads();

        if (full) {
#pragma unroll
            for (int k = 0; k < 8; ++k) {
                unsigned bn = bin_of(((unsigned)rec[k].x) >> 16);
                int dst = sh.bin.base[bn] + lrank[k];
                if (dst < (int)(bn + 1) * BIN_CAP)
                    binbuf[dst] = rec[k];
            }
        } else {
#pragma unroll
            for (int k = 0; k < 8; ++k) {
                if (lrank[k] >= 0) {
                    unsigned bn = bin_of(((unsigned)rec[k].x) >> 16);
                    int dst = sh.bin.base[bn] + lrank[k];
                    if (dst < (int)(bn + 1) * BIN_CAP)
                        binbuf[dst] = rec[k];
                }
            }
        }
    }
}

// ---------------------------------------------------------------------------
// k_sg (R17): TWO BLOCKS PER BIN.  1024 blocks (4/CU, 32 waves/CU) while the
// bin path keeps 512-bin write locality (R16's 1024-bin split amplified
// binbuf write-allocate traffic: WRITE_SIZE 21->38 MB).  Each block handles
// one 49-row half: two direct passes over the L2-hot segment (count, then
// scatter-sort) with a half filter, then the verified 16-wide gather.
// ---------------------------------------------------------------------------
__global__ __launch_bounds__(512, 4) void k_sg(const int* __restrict__ bin_cursor,
                                               const int2* __restrict__ binbuf,
                                               const unsigned* __restrict__ sup,
                                               const float* __restrict__ bias,
                                               float* __restrict__ out) {
    __shared__ int2 sorted_[BIN_CAP];              // 15 KB
    __shared__ int  cnt[64], off[64], cur[64], s[64];
    int blk = blockIdx.x, t = threadIdx.x;
    int bin  = blk >> 1;
    int row0 = bin * ROWS_PER_BIN + (blk & 1) * HALF_ROWS;

    int n = bin_cursor[bin * CUR_STRIDE] - bin * BIN_CAP;
    n = n < 0 ? 0 : (n > BIN_CAP ? BIN_CAP : n);
    const int2* seg = binbuf + (long)bin * BIN_CAP;

    if (t < 64) cnt[t] = 0;
    __syncthreads();

    // pass 1: count own-half rows
    for (int i = t; i < n; i += 512) {
        int rl = (int)(((unsigned)seg[i].x) >> 16) - row0;
        if ((unsigned)rl < HALF_ROWS) atomicAdd(&cnt[rl], 1);
    }
    __syncthreads();

    int v = 0;
    if (t < 64) { v = cnt[t]; s[t] = v; }
    __syncthreads();
#pragma unroll
    for (int o = 1; o < 64; o <<= 1) {
        int xv = 0;
        if (t < 64 && t >= o) xv = s[t - o];
        __syncthreads();
        if (t < 64) s[t] += xv;
        __syncthreads();
    }
    if (t < 64) { off[t] = s[t] - v; cur[t] = 0; }
    __syncthreads();

    // pass 2: scatter own-half records into row-sorted order
    for (int i = t; i < n; i += 512) {
        int2 rec = seg[i];
        int rl = (int)(((unsigned)rec.x) >> 16) - row0;
        if ((unsigned)rl < HALF_ROWS)
            sorted_[off[rl] + atomicAdd(&cur[rl], 1)] = rec;
    }
    __syncthreads();

    int wave = t >> 6, lane = t & 63;
    float bb0 = bias[lane], bb1 = bias[64 + lane];

    for (int rl = wave; rl < HALF_ROWS; rl += 8) {
        int row = row0 + rl;
        if (row >= N_NODES) continue;
        int st = off[rl], nd = cnt[rl];
        float a0 = 0.f, a1 = 0.f;
        for (int i = 0; i < nd; i += 16) {
            int cidx[16]; unsigned u[16]; float vv[16];
#pragma unroll
            for (int j = 0; j < 16; ++j) {
                int ok = (i + j) < nd;
                int2 rec = sorted_[ok ? st + i + j : st];
                cidx[j] = rec.x & 0xffff;
                vv[j]   = ok ? __int_as_float(rec.y) : 0.f;
            }
#pragma unroll
            for (int j = 0; j < 16; ++j)
                u[j] = sup[(long)cidx[j] * 64 + lane];
#pragma unroll
            for (int j = 0; j < 16; ++j) {
                a0 += vv[j] * blo(u[j]);
                a1 += vv[j] * bhi(u[j]);
            }
        }
        out[(long)row * 128 + lane]      = a0 + bb0;
        out[(long)row * 128 + 64 + lane] = a1 + bb1;
    }
}

// ---------------------------------------------------------------------------
extern "C" void kernel_launch(void* const* d_in, const int* in_sizes, int n_in,
                              void* d_out, int out_size, void* d_ws, size_t ws_size,
                              hipStream_t stream) {
    const int*   adj_rows = (const int*)  d_in[0];
    const int*   adj_cols = (const int*)  d_in[1];
    const float* adj_vals = (const float*)d_in[2];
    const float* x        = (const float*)d_in[3];
    const float* W        = (const float*)d_in[4];
    const float* b        = (const float*)d_in[5];
    float* out = (float*)d_out;

    char* ws = (char*)d_ws;
    __bf16*   Wf         = (__bf16*)  (ws + WF_OFF);
    unsigned* sup32      = (unsigned*)(ws + SUP_OFF);
    int2*     binbuf     = (int2*)    (ws + BIN_OFF);
    int*      bin_cursor = (int*)     (ws + CUR_OFF);

    k_prep<<<128, 256, 0, stream>>>(W, Wf, bin_cursor);
    k_fuse<<<NB_GEMM + NB_BIN, 256, 0, stream>>>(x, Wf, sup32,
                                                 adj_rows, adj_cols, adj_vals,
                                                 bin_cursor, binbuf);
    k_sg  <<<NBINS * 2, 512, 0, stream>>>(bin_cursor, binbuf, sup32, b, out);
}

// Round 10
// 151.230 us; speedup vs baseline: 1.0805x; 1.0026x over previous
//
#include <hip/hip_runtime.h>
#include <hip/hip_bf16.h>

#define N_NODES 50000
#define N_EDGES 800000
#define IN_DIM  256
#define OUT_DIM 128

#define NBINS        512      // bins of 98 rows: 512*98 = 50176 >= 50000 (verified)
#define ROWS_PER_BIN 98
#define HALF_ROWS    49       // k_sg processes half a bin per block (R17, verified)
#define BIN_CAP      1920     // mean 1563 + 9 sigma
#define EPB          2048     // edges per bin-block
#define NB_BIN       391      // ceil(800000/2048)
#define NB_GEMM      391      // R18: 512-thr blocks, 8 waves = 8 tiles each
#define CUR_STRIDE   32       // one 128B cacheline per bin cursor

typedef __bf16 bf16x8 __attribute__((ext_vector_type(8)));
typedef float  f32x4  __attribute__((ext_vector_type(4)));

// bin = floor(row/98) via magic: (r*85599)>>23, exact for r < 50176 (verified R14).
__device__ __forceinline__ unsigned bin_of(unsigned r) { return (r * 85599u) >> 23; }
__device__ __forceinline__ float blo(unsigned u) { return __uint_as_float(u << 16); }
__device__ __forceinline__ float bhi(unsigned u) { return __uint_as_float(u & 0xffff0000u); }

// ---------------------------------------------------------------------------
// ws layout (bytes)
// ---------------------------------------------------------------------------
#define WF_OFF   0                      // 64 KB    : Wf bf16 frag-order [4096 slots][8]
#define SUP_OFF  65536                  // 12.8 MB  : support u32 [50000][64] planar-pair
#define BIN_OFF  12865536               // 7.86 MB  : binbuf int2[512*1920]
#define CUR_OFF  20729856               // 64 KB    : bin_cursor int[512*CUR_STRIDE]

// ---------------------------------------------------------------------------
// prep (R12, verified): Wf = W in MFMA B-fragment order.
// Slot s (16B = 8 halfs): n = s>>9, ks = (s>>6)&7, lane = s&63, m = lane&15,
// quad = (lane>>4); half j holds W[(quad*8+ks*32+j)*OUT_DIM + (n*16+m)].
// ---------------------------------------------------------------------------
__global__ void k_prep(const float* __restrict__ W, __bf16* __restrict__ Wf,
                       int* __restrict__ bin_cursor) {
    int t = blockIdx.x * 256 + threadIdx.x;
    if (t < 32768) {
        int s = t >> 3, j = t & 7;
        int nrow = ((s >> 9) << 4) | (s & 15);                 // n*16 + m
        int k    = (((s >> 4) & 3) << 3) | (((s >> 6) & 7) << 5) | j;
        Wf[t] = (__bf16)W[k * OUT_DIM + nrow];
    }
    if (t < NBINS) bin_cursor[t * CUR_STRIDE] = t * BIN_CAP;
}

// ---------------------------------------------------------------------------
// k_fuse (R18): 512-thread blocks.
//   GEMM blocks [0, NB_GEMM): 8 waves share ONE 64 KB Wf staging (was 4) ->
//     16 waves/CU at 2 blocks/CU (2x TLP of R15) and Wf staging traffic
//     halves (391 stagings vs 782).  Per-wave body = verified R12, verbatim.
//   BIN blocks [NB_GEMM, +NB_BIN): verified lean binning, 4 edges/thread.
// ---------------------------------------------------------------------------
__global__ __launch_bounds__(512, 4) void k_fuse(const float* __restrict__ x,
                                                 const __bf16* __restrict__ Wf,
                                                 unsigned* __restrict__ sup32,
                                                 const int* __restrict__ rows,
                                                 const int* __restrict__ cols,
                                                 const float* __restrict__ vals,
                                                 int* __restrict__ bin_cursor,
                                                 int2* __restrict__ binbuf) {
    __shared__ union {
        uint4 sB[4096];                                   // 64 KB : gemm Wf tile
        struct { int cur[NBINS]; int base[NBINS]; } bin;  // 4 KB  : bin counters
    } sh;
    int t = threadIdx.x;

    if (blockIdx.x < NB_GEMM) {
        // ---------------- gemm path (R12 body, 8 waves/block) ----------------
        const uint4* wf4 = (const uint4*)Wf;
#pragma unroll
        for (int r = 0; r < 8; ++r) sh.sB[r * 512 + t] = wf4[r * 512 + t];
        __syncthreads();

        int  wave = t >> 6;
        int  lane = t & 63;
        long tile = (long)blockIdx.x * 8 + wave;       // 0..3127
        if (tile >= 3125) return;                      // after the barrier: safe
        int  m    = lane & 15;
        int  quad = lane >> 4;

        // A: lane (m,quad) reads row tile*16+m; 3125*16 == 50000 -> no guard.
        const float* aprow = x + (tile * 16 + m) * IN_DIM + quad * 8;

        float4 fa[16];
#pragma unroll
        for (int ks = 0; ks < 8; ++ks) {
            fa[2 * ks]     = *(const float4*)(aprow + ks * 32);
            fa[2 * ks + 1] = *(const float4*)(aprow + ks * 32 + 4);
        }
        bf16x8 ab[8];
#pragma unroll
        for (int ks = 0; ks < 8; ++ks) {
            float4 f0 = fa[2 * ks];
            float4 f1 = fa[2 * ks + 1];
            ab[ks] = (bf16x8){(__bf16)f0.x, (__bf16)f0.y, (__bf16)f0.z, (__bf16)f0.w,
                              (__bf16)f1.x, (__bf16)f1.y, (__bf16)f1.z, (__bf16)f1.w};
        }

        f32x4 acc[8];
#pragma unroll
        for (int n = 0; n < 8; ++n) acc[n] = (f32x4){0, 0, 0, 0};

        const __bf16* sbh = (const __bf16*)sh.sB;
#pragma unroll
        for (int ks = 0; ks < 8; ++ks) {
#pragma unroll
            for (int n = 0; n < 8; ++n) {
                // slot (n*8+ks)*64 + lane : consecutive lanes -> consecutive 16B
                bf16x8 bfr = *(const bf16x8*)(sbh + (((n * 8 + ks) * 64 + lane) << 3));
                acc[n] = __builtin_amdgcn_mfma_f32_16x16x32_bf16(ab[ks], bfr, acc[n], 0, 0, 0);
            }
        }

        // planar-pair epilogue (verified R7): word j = n*16+m = ch j | ch j+64
        unsigned* op = sup32 + (long)tile * 16 * 64;
#pragma unroll
        for (int r = 0; r < 4; ++r) {
#pragma unroll
            for (int n = 0; n < 4; ++n) {
                __bf16 lo = (__bf16)acc[n][r], hi = (__bf16)acc[n + 4][r];
                unsigned w = (unsigned)*(unsigned short*)&lo |
                             ((unsigned)*(unsigned short*)&hi << 16);
                op[(quad * 4 + r) * 64 + n * 16 + m] = w;
            }
        }
    } else {
        // ---------------- bin path (verified lean body, 512 threads) ----------------
        long e0 = (long)(blockIdx.x - NB_GEMM) * EPB;
        sh.bin.cur[t] = 0;
        __syncthreads();

        int2 rec[4];
        int  lrank[4];
        bool full = (e0 + EPB <= N_EDGES);   // true for 390 of 391 blocks

        if (full) {
#pragma unroll
            for (int k = 0; k < 4; ++k) {
                long e = e0 + k * 512 + t;
                unsigned r = (unsigned)rows[e];
                unsigned c = (unsigned)cols[e];
                float    w = vals[e];
                rec[k]   = make_int2((int)((r << 16) | c), __float_as_int(w));
                lrank[k] = atomicAdd(&sh.bin.cur[bin_of(r)], 1);
            }
        } else {
#pragma unroll
            for (int k = 0; k < 4; ++k) {
                long e = e0 + k * 512 + t;
                lrank[k] = -1;
                if (e < N_EDGES) {
                    unsigned r = (unsigned)rows[e];
                    unsigned c = (unsigned)cols[e];
                    float    w = vals[e];
                    rec[k]   = make_int2((int)((r << 16) | c), __float_as_int(w));
                    lrank[k] = atomicAdd(&sh.bin.cur[bin_of(r)], 1);
                }
            }
        }
        __syncthreads();

        sh.bin.base[t] = atomicAdd(&bin_cursor[t * CUR_STRIDE], sh.bin.cur[t]);
        __syncthreads();

        if (full) {
#pragma unroll
            for (int k = 0; k < 4; ++k) {
                unsigned bn = bin_of(((unsigned)rec[k].x) >> 16);
                int dst = sh.bin.base[bn] + lrank[k];
                if (dst < (int)(bn + 1) * BIN_CAP)
                    binbuf[dst] = rec[k];
            }
        } else {
#pragma unroll
            for (int k = 0; k < 4; ++k) {
                if (lrank[k] >= 0) {
                    unsigned bn = bin_of(((unsigned)rec[k].x) >> 16);
                    int dst = sh.bin.base[bn] + lrank[k];
                    if (dst < (int)(bn + 1) * BIN_CAP)
                        binbuf[dst] = rec[k];
                }
            }
        }
    }
}

// ---------------------------------------------------------------------------
// k_sg (R17, verified): TWO BLOCKS PER BIN -> 1024 blocks, 4/CU.  Each block
// handles one 49-row half: two filtered passes over the L2-hot segment
// (count, scatter-sort), then the verified 16-wide gather.
// ---------------------------------------------------------------------------
__global__ __launch_bounds__(512, 4) void k_sg(const int* __restrict__ bin_cursor,
                                               const int2* __restrict__ binbuf,
                                               const unsigned* __restrict__ sup,
                                               const float* __restrict__ bias,
                                               float* __restrict__ out) {
    __shared__ int2 sorted_[BIN_CAP];              // 15 KB
    __shared__ int  cnt[64], off[64], cur[64], s[64];
    int blk = blockIdx.x, t = threadIdx.x;
    int bin  = blk >> 1;
    int row0 = bin * ROWS_PER_BIN + (blk & 1) * HALF_ROWS;

    int n = bin_cursor[bin * CUR_STRIDE] - bin * BIN_CAP;
    n = n < 0 ? 0 : (n > BIN_CAP ? BIN_CAP : n);
    const int2* seg = binbuf + (long)bin * BIN_CAP;

    if (t < 64) cnt[t] = 0;
    __syncthreads();

    // pass 1: count own-half rows
    for (int i = t; i < n; i += 512) {
        int rl = (int)(((unsigned)seg[i].x) >> 16) - row0;
        if ((unsigned)rl < HALF_ROWS) atomicAdd(&cnt[rl], 1);
    }
    __syncthreads();

    int v = 0;
    if (t < 64) { v = cnt[t]; s[t] = v; }
    __syncthreads();
#pragma unroll
    for (int o = 1; o < 64; o <<= 1) {
        int xv = 0;
        if (t < 64 && t >= o) xv = s[t - o];
        __syncthreads();
        if (t < 64) s[t] += xv;
        __syncthreads();
    }
    if (t < 64) { off[t] = s[t] - v; cur[t] = 0; }
    __syncthreads();

    // pass 2: scatter own-half records into row-sorted order
    for (int i = t; i < n; i += 512) {
        int2 rec = seg[i];
        int rl = (int)(((unsigned)rec.x) >> 16) - row0;
        if ((unsigned)rl < HALF_ROWS)
            sorted_[off[rl] + atomicAdd(&cur[rl], 1)] = rec;
    }
    __syncthreads();

    int wave = t >> 6, lane = t & 63;
    float bb0 = bias[lane], bb1 = bias[64 + lane];

    for (int rl = wave; rl < HALF_ROWS; rl += 8) {
        int row = row0 + rl;
        if (row >= N_NODES) continue;
        int st = off[rl], nd = cnt[rl];
        float a0 = 0.f, a1 = 0.f;
        for (int i = 0; i < nd; i += 16) {
            int cidx[16]; unsigned u[16]; float vv[16];
#pragma unroll
            for (int j = 0; j < 16; ++j) {
                int ok = (i + j) < nd;
                int2 rec = sorted_[ok ? st + i + j : st];
                cidx[j] = rec.x & 0xffff;
                vv[j]   = ok ? __int_as_float(rec.y) : 0.f;
            }
#pragma unroll
            for (int j = 0; j < 16; ++j)
                u[j] = sup[(long)cidx[j] * 64 + lane];
#pragma unroll
            for (int j = 0; j < 16; ++j) {
                a0 += vv[j] * blo(u[j]);
                a1 += vv[j] * bhi(u[j]);
            }
        }
        out[(long)row * 128 + lane]      = a0 + bb0;
        out[(long)row * 128 + 64 + lane] = a1 + bb1;
    }
}

// ---------------------------------------------------------------------------
extern "C" void kernel_launch(void* const* d_in, const int* in_sizes, int n_in,
                              void* d_out, int out_size, void* d_ws, size_t ws_size,
                              hipStream_t stream) {
    const int*   adj_rows = (const int*)  d_in[0];
    const int*   adj_cols = (const int*)  d_in[1];
    const float* adj_vals = (const float*)d_in[2];
    const float* x        = (const float*)d_in[3];
    const float* W        = (const float*)d_in[4];
    const float* b        = (const float*)d_in[5];
    float* out = (float*)d_out;

    char* ws = (char*)d_ws;
    __bf16*   Wf         = (__bf16*)  (ws + WF_OFF);
    unsigned* sup32      = (unsigned*)(ws + SUP_OFF);
    int2*     binbuf     = (int2*)    (ws + BIN_OFF);
    int*      bin_cursor = (int*)     (ws + CUR_OFF);

    k_prep<<<128, 256, 0, stream>>>(W, Wf, bin_cursor);
    k_fuse<<<NB_GEMM + NB_BIN, 512, 0, stream>>>(x, Wf, sup32,
                                                 adj_rows, adj_cols, adj_vals,
                                                 bin_cursor, binbuf);
    k_sg  <<<NBINS * 2, 512, 0, stream>>>(bin_cursor, binbuf, sup32, b, out);
}